// Round 4
// baseline (391.818 us; speedup 1.0000x reference)
//
#include <hip/hip_runtime.h>
#include <hip/hip_fp16.h>

#define NN 20000      // nodes
#define NE 320000     // edges
#define SS 2          // feature axis
#define FIN 128
#define FH 246

typedef _Float16 f16x8 __attribute__((ext_vector_type(8)));
typedef float f32x4 __attribute__((ext_vector_type(4)));

// ---------------- degree histogram ----------------
__global__ void degree_kernel(const int* __restrict__ src, const int* __restrict__ dst,
                              int* __restrict__ deg_out, int* __restrict__ deg_in) {
    int e = blockIdx.x * blockDim.x + threadIdx.x;
    if (e < NE) {
        atomicAdd(&deg_out[src[e]], 1);
        atomicAdd(&deg_in[dst[e]], 1);
    }
}

// ---------------- norms + parallel CSR range allocation (fused) ----------------
// ranges PADDED to multiples of 4 (pad slots get src=NN -> zero row) so the
// aggregate can do one aligned ushort4 index load per 4 edges, no tail loop.
__global__ void alloc_kernel(const int* __restrict__ deg_out, const int* __restrict__ deg_in,
                             float* __restrict__ norm_out, float* __restrict__ norm_in,
                             int* __restrict__ row_start, int* __restrict__ cursor,
                             int* __restrict__ counter) {
    __shared__ int smem[256];
    __shared__ int base_s;
    int tid = threadIdx.x;
    int i = blockIdx.x * 256 + tid;
    int v  = (i < NN) ? deg_in[i] : 0;
    int vp = (v + 3) & ~3;                 // padded degree
    smem[tid] = vp;
    __syncthreads();
    for (int off = 1; off < 256; off <<= 1) {
        int t = (tid >= off) ? smem[tid - off] : 0;
        __syncthreads();
        smem[tid] += t;
        __syncthreads();
    }
    int incl = smem[tid];
    if (tid == 0) base_s = atomicAdd(counter, smem[255]);
    __syncthreads();
    if (i < NN) {
        int excl = base_s + incl - vp;     // multiple of 4 by construction
        row_start[i] = excl;
        cursor[i]    = excl;
        norm_out[i] = rsqrtf(fmaxf((float)deg_out[i], 1.0f));
        norm_in[i]  = rsqrtf(fmaxf((float)v, 1.0f));
    }
}

// ---------------- scatter edges into CSR (ushort indices: NN < 65536) ----------
__global__ void scatter_kernel(const int* __restrict__ src, const int* __restrict__ dst,
                               int* __restrict__ cursor, ushort* __restrict__ sorted_src) {
    int e = blockIdx.x * blockDim.x + threadIdx.x;
    if (e < NE) {
        int d = dst[e];
        int pos = atomicAdd(&cursor[d], 1);
        sorted_src[pos] = (ushort)src[e];
    }
}

// ---------------- fill pad slots with src=NN (the zero/dead row) ----------------
__global__ void pad_fill(const int* __restrict__ row_start, const int* __restrict__ deg_in,
                         ushort* __restrict__ sorted_src) {
    int n = blockIdx.x * 256 + threadIdx.x;
    if (n < NN) {
        int d = deg_in[n];
        int beg = row_start[n] + d;
        int end = row_start[n] + ((d + 3) & ~3);
        for (int p = beg; p < end; ++p) sorted_src[p] = (ushort)NN;
    }
}

// ---------------- W pre-split (all 3 layers in one launch) ----------------
__global__ void convert_w_all(const float* __restrict__ W0, const float* __restrict__ W1,
                              const float* __restrict__ W2,
                              ushort* __restrict__ Wh0, ushort* __restrict__ Wl0,
                              ushort* __restrict__ Wh1, ushort* __restrict__ Wl1,
                              ushort* __restrict__ Wh2, ushort* __restrict__ Wl2) {
    int n = blockIdx.x, k = threadIdx.x;
    const float* W; ushort* Wh; ushort* Wl; int K;
    if (blockIdx.y == 0)      { W = W0; Wh = Wh0; Wl = Wl0; K = FIN; }
    else if (blockIdx.y == 1) { W = W1; Wh = Wh1; Wl = Wl1; K = FH; }
    else                      { W = W2; Wh = Wh2; Wl = Wl2; K = FH; }
    float v = (k < K && n < 246) ? W[k * 246 + n] : 0.f;
    _Float16 h = (_Float16)v;
    _Float16 l = (_Float16)(v - (float)h);
    Wh[n * 256 + k] = *(ushort*)&h;
    Wl[n * 256 + k] = *(ushort*)&l;
}

__global__ void init_out(float* __restrict__ out, const float* __restrict__ fcb,
                         float* __restrict__ norm_out) {
    int i = blockIdx.x * 256 + threadIdx.x;
    if (i < NN) out[i] = fcb[0];
    if (i == 0) norm_out[NN] = 0.f;   // dead-norm entry for layer-0 pad edges
}

// ---------------- XCD-pinned chunk-tiled gather-aggregate, split-f16 output ----------
// r21: + index PREFETCH (ushort4 for iter i+1 issued before iter i's gathers --
// compiler cannot speculate past the loop bound, so the idx->gather dependency
// serialized every iteration) and NONTEMPORAL output stores (40 MB write stream
// was cycling through 4 MB L2s, evicting gather-resident rows). NT store via
// unsigned long long (builtin rejects HIP vector types).
// Geometry r18-proven: 16 lanes/node, 256B chunks, 4 nodes/wave (r19 A/B: time
// follows wave-iters x lines, NOT locality). Pure segment-sum (norms folded
// into producer); ushort4 packed indices, ranges 4-padded (pad src=NN -> zero
// row). NORM=true only for layer 0 (feat can't be prescaled in-place).
template<int F4ROW, int NCH, bool NORM>
__global__ void aggregate4(const float* __restrict__ h,
                           const int* __restrict__ row_start,
                           const int* __restrict__ deg_in,
                           const ushort* __restrict__ sorted_src,
                           const float* __restrict__ norm_out,
                           const float* __restrict__ norm_in,
                           ushort* __restrict__ Ah, ushort* __restrict__ Al) {
    int g  = threadIdx.x >> 4;              // 0..7: node sub-index
    int l  = threadIdx.x & 15;              // float4 within chunk
    int cb = blockIdx.x & (NCH - 1);        // chunk (XCD-pinned axis)
    int nb = blockIdx.x / NCH;              // node group
    int n  = nb * 8 + g;
    if (n >= NN) return;
    int idx = cb * 16 + l;                  // < F4ROW (= NCH*16)
    const float4* hv = (const float4*)h;
    int beg = row_start[n];
    int end = beg + ((deg_in[n] + 3) & ~3);
    float4 acc = {0.f, 0.f, 0.f, 0.f};
    ushort4 ss;
    if (beg < end) ss = *(const ushort4*)&sorted_src[beg];   // 8B aligned (beg%4==0)
    for (int i = beg; i < end; i += 4) {
        ushort4 cur = ss;
        if (i + 4 < end) ss = *(const ushort4*)&sorted_src[i + 4];   // prefetch
        int s0 = cur.x, s1 = cur.y, s2 = cur.z, s3 = cur.w;
        if (NORM) {
            float n0 = norm_out[s0], n1 = norm_out[s1];
            float n2 = norm_out[s2], n3 = norm_out[s3];
            float4 v0 = hv[(size_t)(s0 < NN ? s0 : NN - 1) * F4ROW + idx];
            float4 v1 = hv[(size_t)(s1 < NN ? s1 : NN - 1) * F4ROW + idx];
            float4 v2 = hv[(size_t)(s2 < NN ? s2 : NN - 1) * F4ROW + idx];
            float4 v3 = hv[(size_t)(s3 < NN ? s3 : NN - 1) * F4ROW + idx];
            acc.x += v0.x * n0 + v1.x * n1 + v2.x * n2 + v3.x * n3;
            acc.y += v0.y * n0 + v1.y * n1 + v2.y * n2 + v3.y * n3;
            acc.z += v0.z * n0 + v1.z * n1 + v2.z * n2 + v3.z * n3;
            acc.w += v0.w * n0 + v1.w * n1 + v2.w * n2 + v3.w * n3;
        } else {
            float4 v0 = hv[(size_t)s0 * F4ROW + idx];   // s=NN -> zeroed pad row
            float4 v1 = hv[(size_t)s1 * F4ROW + idx];
            float4 v2 = hv[(size_t)s2 * F4ROW + idx];
            float4 v3 = hv[(size_t)s3 * F4ROW + idx];
            acc.x += v0.x + v1.x + v2.x + v3.x;
            acc.y += v0.y + v1.y + v2.y + v3.y;
            acc.z += v0.z + v1.z + v2.z + v3.z;
            acc.w += v0.w + v1.w + v2.w + v3.w;
        }
    }
    float ni = norm_in[n];
    float v[4] = {acc.x * ni, acc.y * ni, acc.z * ni, acc.w * ni};
    ushort hp[4], lp[4];
#pragma unroll
    for (int j = 0; j < 4; ++j) {
        _Float16 hh = (_Float16)v[j];
        _Float16 ll = (_Float16)(v[j] - (float)hh);
        hp[j] = *(ushort*)&hh;
        lp[j] = *(ushort*)&ll;
    }
    unsigned long long hv64, lv64;
    __builtin_memcpy(&hv64, hp, 8);
    __builtin_memcpy(&lv64, lp, 8);
    __builtin_nontemporal_store(hv64, (unsigned long long*)Ah + (size_t)n * F4ROW + idx);
    __builtin_nontemporal_store(lv64, (unsigned long long*)Al + (size_t)n * F4ROW + idx);
}

// ---------------- split-f16 MFMA GEMM, pre-split A ----------
// r21: wave tile 32x64 -> 64x64 (block 128Mx128N, 4 waves 2x2). Old shape was
// LDS-read-bound: 24 MFMA (~120cy) vs 12 ds_read_b128 (~144cy) per wave-K-tile.
// New: 48 MFMA (~240cy) vs 16 reads (~192cy) -> MFMA-bound, and B staged once
// per 128 M-rows instead of 64. M padded to 40064 (zeroed pad rows in Ah/Al),
// C-writes guarded m<40000.
// D[m,c] = relu( A[m,:] . W[:,c] + b[c] ) [* norm_out fold], A = pre-split f16
// hi/lo, W pre-split f16 hi/lo [256][256]; acc += Ah*Wh + Al*Wh + Ah*Wl.
// FUSE: relu -> *fc_w -> mean_s -> 16-lane reduce -> atomicAdd(out[node], 0.5p).
template<int KP, bool FUSE>
__global__ __launch_bounds__(256) void gemm_split(const ushort* __restrict__ Ah,
                                                  const ushort* __restrict__ Al,
                                                  const ushort* __restrict__ Wh,
                                                  const ushort* __restrict__ Wl,
                                                  const float* __restrict__ b,
                                                  void* __restrict__ outv,
                                                  const float* __restrict__ fcw,
                                                  const float* __restrict__ nrm) {
    constexpr int NT = KP / 32;
    constexpr int AS = KP / 8;             // A row stride in uint4
    __shared__ __align__(16) _Float16 Ah_s[128][40];
    __shared__ __align__(16) _Float16 Al_s[128][40];
    __shared__ __align__(16) _Float16 Bh_s[128][40];
    __shared__ __align__(16) _Float16 Bl_s[128][40];

    int tid  = threadIdx.x;
    int m0   = blockIdx.x * 128;
    int n0   = blockIdx.y * 128;
    int wave = tid >> 6, lane = tid & 63;
    int wm = wave >> 1, wn = wave & 1;
    int lr = lane & 15, quad = lane >> 4;

    f32x4 acc[4][4];
#pragma unroll
    for (int mi = 0; mi < 4; ++mi)
#pragma unroll
        for (int ni = 0; ni < 4; ++ni) acc[mi][ni] = {0.f, 0.f, 0.f, 0.f};

    const uint4* Ahv = (const uint4*)Ah;
    const uint4* Alv = (const uint4*)Al;
    const uint4* Whv = (const uint4*)Wh;   // row stride 32 uint4
    const uint4* Wlv = (const uint4*)Wl;

    for (int t0 = 0; t0 < NT; ++t0) {
        // ---- stage A+B: 128 rows x 32 k each, hi+lo (2 uint4/thread each)
#pragma unroll
        for (int it = 0; it < 2; ++it) {
            int f = it * 256 + tid;
            int rn = f >> 2, q = f & 3;
            size_t abase = (size_t)(m0 + rn) * AS + t0 * 4 + q;
            *(uint4*)&Ah_s[rn][q * 8] = Ahv[abase];
            *(uint4*)&Al_s[rn][q * 8] = Alv[abase];
            size_t bbase = (size_t)(n0 + rn) * 32 + t0 * 4 + q;
            *(uint4*)&Bh_s[rn][q * 8] = Whv[bbase];
            *(uint4*)&Bl_s[rn][q * 8] = Wlv[bbase];
        }
        __syncthreads();

        f16x8 ah[4], al[4], bh[4], bl[4];
#pragma unroll
        for (int mi = 0; mi < 4; ++mi) {
            ah[mi] = *(const f16x8*)&Ah_s[wm * 64 + mi * 16 + lr][quad * 8];
            al[mi] = *(const f16x8*)&Al_s[wm * 64 + mi * 16 + lr][quad * 8];
        }
#pragma unroll
        for (int ni = 0; ni < 4; ++ni) {
            bh[ni] = *(const f16x8*)&Bh_s[wn * 64 + ni * 16 + lr][quad * 8];
            bl[ni] = *(const f16x8*)&Bl_s[wn * 64 + ni * 16 + lr][quad * 8];
        }
#pragma unroll
        for (int mi = 0; mi < 4; ++mi)
#pragma unroll
            for (int ni = 0; ni < 4; ++ni) {
                acc[mi][ni] = __builtin_amdgcn_mfma_f32_16x16x32_f16(ah[mi], bh[ni], acc[mi][ni], 0, 0, 0);
                acc[mi][ni] = __builtin_amdgcn_mfma_f32_16x16x32_f16(al[mi], bh[ni], acc[mi][ni], 0, 0, 0);
                acc[mi][ni] = __builtin_amdgcn_mfma_f32_16x16x32_f16(ah[mi], bl[ni], acc[mi][ni], 0, 0, 0);
            }
        __syncthreads();
    }

    if (FUSE) {
        float* out = (float*)outv;
#pragma unroll
        for (int mi = 0; mi < 4; ++mi) {
#pragma unroll
            for (int i = 0; i < 4; ++i) {
                float p = 0.f;
#pragma unroll
                for (int ni = 0; ni < 4; ++ni) {
                    int c = n0 + wn * 64 + ni * 16 + lr;
                    if (c < 246)
                        p += fmaxf(acc[mi][ni][i] + b[c], 0.f) * fcw[c];
                }
#pragma unroll
                for (int off = 8; off > 0; off >>= 1)
                    p += __shfl_down(p, off, 16);
                int m = m0 + wm * 64 + mi * 16 + quad * 4 + i;
                if (lr == 0 && m < NN * SS)
                    atomicAdd(&out[m >> 1], 0.5f * p);
            }
        }
    } else {
        float* outF = (float*)outv;    // fp32 [M][256]; cols>=246 get 0 (acc=0, bj=0)
#pragma unroll
        for (int ni = 0; ni < 4; ++ni) {
            int c = n0 + wn * 64 + ni * 16 + lr;
            float bj = (c < 246) ? b[c] : 0.f;
#pragma unroll
            for (int mi = 0; mi < 4; ++mi)
#pragma unroll
                for (int i = 0; i < 4; ++i) {
                    int m = m0 + wm * 64 + mi * 16 + quad * 4 + i;
                    if (m < NN * SS) {
                        float no = nrm[m >> 1];
                        outF[(size_t)m * 256 + c] = fmaxf(acc[mi][ni][i] + bj, 0.f) * no;
                    }
                }
        }
    }
}

extern "C" void kernel_launch(void* const* d_in, const int* in_sizes, int n_in,
                              void* d_out, int out_size, void* d_ws, size_t ws_size,
                              hipStream_t stream) {
    const float* feat = (const float*)d_in[0];
    const int*   src  = (const int*)d_in[1];
    const int*   dst  = (const int*)d_in[2];
    const float* W0   = (const float*)d_in[3];
    const float* b0   = (const float*)d_in[4];
    const float* W1   = (const float*)d_in[5];
    const float* b1   = (const float*)d_in[6];
    const float* W2   = (const float*)d_in[7];
    const float* b2   = (const float*)d_in[8];
    const float* fcw  = (const float*)d_in[9];
    const float* fcb  = (const float*)d_in[10];
    float* out = (float*)d_out;

    char* ws = (char*)d_ws;
    size_t off = 0;
    auto alloc = [&](size_t bytes) {
        void* p = ws + off;
        off = (off + bytes + 255) & ~(size_t)255;
        return p;
    };
    int*    deg_out_i = (int*)alloc((2 * NN + 64) * sizeof(int));
    int*    deg_in_i  = deg_out_i + NN;
    int*    counter   = deg_out_i + 2 * NN;
    int*    row_start = (int*)alloc(NN * sizeof(int));
    int*    cursor    = (int*)alloc(NN * sizeof(int));
    ushort* sorted    = (ushort*)alloc((NE + 3 * NN + 16) * sizeof(ushort));
    float*  norm_out  = (float*)alloc((NN + 1) * sizeof(float));   // [NN] = 0 (pad)
    float*  norm_in   = (float*)alloc(NN * sizeof(float));
    ushort* Wh0 = (ushort*)alloc(256 * 256 * sizeof(ushort));
    ushort* Wl0 = (ushort*)alloc(256 * 256 * sizeof(ushort));
    ushort* Wh1 = (ushort*)alloc(256 * 256 * sizeof(ushort));
    ushort* Wl1 = (ushort*)alloc(256 * 256 * sizeof(ushort));
    ushort* Wh2 = (ushort*)alloc(256 * 256 * sizeof(ushort));
    ushort* Wl2 = (ushort*)alloc(256 * 256 * sizeof(ushort));
    ushort* Ahb = (ushort*)alloc((size_t)(NN * SS + 64) * 256 * sizeof(ushort));  // split A hi (+M pad)
    ushort* Alb = (ushort*)alloc((size_t)(NN * SS + 64) * 256 * sizeof(ushort));  // split A lo (+M pad)
    float*  bufH = (float*)alloc(((size_t)NN * SS * 256 + 512) * sizeof(float)); // +zero pad row

    hipMemsetAsync(deg_out_i, 0, (2 * NN + 1) * sizeof(int), stream);
    hipMemsetAsync(bufH + (size_t)NN * 512, 0, 512 * sizeof(float), stream);  // pad row (src=NN)
    // M-pad rows for the 128-wide gemm tiles (40000..40063), both A layouts
    hipMemsetAsync(Ahb + (size_t)NN * SS * 128, 0, 64 * 128 * sizeof(ushort), stream);
    hipMemsetAsync(Alb + (size_t)NN * SS * 128, 0, 64 * 128 * sizeof(ushort), stream);
    hipMemsetAsync(Ahb + (size_t)NN * SS * 256, 0, 64 * 256 * sizeof(ushort), stream);
    hipMemsetAsync(Alb + (size_t)NN * SS * 256, 0, 64 * 256 * sizeof(ushort), stream);

    degree_kernel<<<(NE + 255) / 256, 256, 0, stream>>>(src, dst, deg_out_i, deg_in_i);
    alloc_kernel<<<(NN + 255) / 256, 256, 0, stream>>>(deg_out_i, deg_in_i, norm_out, norm_in,
                                                       row_start, cursor, counter);
    pad_fill<<<(NN + 255) / 256, 256, 0, stream>>>(row_start, deg_in_i, sorted);
    scatter_kernel<<<(NE + 255) / 256, 256, 0, stream>>>(src, dst, cursor, sorted);

    convert_w_all<<<dim3(256, 3), 256, 0, stream>>>(W0, W1, W2, Wh0, Wl0, Wh1, Wl1, Wh2, Wl2);
    init_out<<<(NN + 255) / 256, 256, 0, stream>>>(out, fcb, norm_out);

    const int NB8 = (NN + 7) / 8;             // 2500 node groups (8 nodes/block)
    const int GX  = (NN * SS + 127) / 128;    // 313 M-tiles
    dim3 ggrid(GX, 2);

    // Layer 0: feat [N][2*128] -> agg (norm gathers, row clamp) -> gemm(*norm_out) -> bufH
    aggregate4<64, 4, true><<<NB8 * 4, 128, 0, stream>>>(feat, row_start, deg_in_i, sorted,
                                                         norm_out, norm_in, Ahb, Alb);
    gemm_split<FIN, false><<<ggrid, 256, 0, stream>>>(Ahb, Alb, Wh0, Wl0, b0, bufH, fcw, norm_out);

    // Layer 1: bufH (pre-scaled by norm_out) -> pure-sum agg -> gemm(*norm_out) -> bufH
    aggregate4<128, 8, false><<<NB8 * 8, 128, 0, stream>>>(bufH, row_start, deg_in_i, sorted,
                                                           norm_out, norm_in, Ahb, Alb);
    gemm_split<256, false><<<ggrid, 256, 0, stream>>>(Ahb, Alb, Wh1, Wl1, b1, bufH, fcw, norm_out);

    // Layer 2: bufH -> pure-sum agg -> fused gemm -> out (atomicAdd; out pre-set to fcb)
    aggregate4<128, 8, false><<<NB8 * 8, 128, 0, stream>>>(bufH, row_start, deg_in_i, sorted,
                                                           norm_out, norm_in, Ahb, Alb);
    gemm_split<256, true><<<ggrid, 256, 0, stream>>>(Ahb, Alb, Wh2, Wl2, b2, out, fcw, norm_out);
}